// Round 5
// baseline (5531.183 us; speedup 1.0000x reference)
//
#include <hip/hip_runtime.h>
#include <cstdint>
#include <cstddef>

typedef unsigned short u16;
typedef float f32x4 __attribute__((ext_vector_type(4)));
typedef __bf16 bf16x8 __attribute__((ext_vector_type(8)));

#define B_DIM   8192
#define IN_DIM  1024
#define HID_DIM 4096
#define OUT_DIM 1024
#define NEXP    8

// ---------- helpers ----------
__device__ __forceinline__ u16 f2b(float f) {
    uint32_t u = __builtin_bit_cast(uint32_t, f);
    u += 0x7fffu + ((u >> 16) & 1u);      // RNE
    return (u16)(u >> 16);
}
__device__ __forceinline__ float b2f(u16 b) {
    uint32_t u = ((uint32_t)b) << 16;
    return __builtin_bit_cast(float, u);
}
// tanh-form GELU via one v_exp_f32: gelu(x) = x * e/(e+1), e = exp(2*y).
__device__ __forceinline__ float gelu_fast(float x) {
    float y = x * (0.7978845608f + 0.03567740814f * x * x);
    float a = fminf(y * 2.8853900818f, 80.0f);     // 2*log2(e)*y, clamp overflow
    float e = __builtin_amdgcn_exp2f(a);
    return x * e * __builtin_amdgcn_rcpf(e + 1.0f);
}
__device__ __forceinline__ void async_cp16(const void* g, void* l) {
    __builtin_amdgcn_global_load_lds(
        (const __attribute__((address_space(1))) void*)g,
        (__attribute__((address_space(3))) void*)l,
        16, 0, 0);
}

// ---------- fp32 -> bf16 convert ----------
__global__ __launch_bounds__(256)
void cvt_bf16(const float* __restrict__ in, u16* __restrict__ out, int n4) {
    int i = blockIdx.x * 256 + threadIdx.x;
    if (i >= n4) return;
    float4 v = *(const float4*)&in[(size_t)i * 4];
    uint2 o;
    o.x = (uint32_t)f2b(v.x) | ((uint32_t)f2b(v.y) << 16);
    o.y = (uint32_t)f2b(v.z) | ((uint32_t)f2b(v.w) << 16);
    *(uint2*)&out[(size_t)i * 4] = o;
}

// ---------- transpose both expert weights: [K,N] fp32 -> [N,K] bf16 ----------
__global__ __launch_bounds__(256)
void transpose_cvt2(const float* __restrict__ W1e, u16* __restrict__ w1t,
                    const float* __restrict__ W2e, u16* __restrict__ w2t) {
    __shared__ float tile[32][33];
    const float* W; u16* Wt; int K, N, n0, k0;
    if (blockIdx.z == 0) {
        W = W1e; Wt = w1t; K = IN_DIM; N = HID_DIM;
        n0 = blockIdx.x * 32; k0 = blockIdx.y * 32;
    } else {
        W = W2e; Wt = w2t; K = HID_DIM; N = OUT_DIM;
        n0 = blockIdx.y * 32; k0 = blockIdx.x * 32;
    }
    const int tx = threadIdx.x & 31, ty = threadIdx.x >> 5;   // ty 0..7
#pragma unroll
    for (int i = 0; i < 4; ++i) {
        int k = k0 + ty + i * 8;
        tile[ty + i * 8][tx] = W[(size_t)k * N + n0 + tx];
    }
    __syncthreads();
#pragma unroll
    for (int i = 0; i < 4; ++i) {
        int n = n0 + ty + i * 8;
        Wt[(size_t)n * K + k0 + tx] = f2b(tile[tx][ty + i * 8]);
    }
}

// ---------- 256x512 bf16 GEMM (GEMM1): staging-minimized tile ----------
// C[M,N] = A[M,K] * Bt[N,K]^T + bias, bf16 out.
// 1024 thr = 16 waves (2M x 8N), per-wave 128x64 (acc[8][4]). BK=32.
// Rationale (R4 model): steady-state wall tracks staged bytes at ~10-11
// B/cy/CU; 256x512 amortizes the A-panel over 512 cols -> staged
// bytes/output x0.73, and grid=256 blocks = ONE generation (no second
// prologue/epilogue). 3-buffer LDS (144 KiB), staged 2 tiles ahead,
// counted vmcnt(3) per tile (3 loads/thread/tile: A x1, B x2).
// Frag/swizzle patterns identical to the proven R3 kernel (0 conflicts):
// stage chunk lc = ((tid&3)^((tid>>3)&3))*8; read chunk (quad^((lr>>1)&3)).
// Involution check for this geometry: stored row r permutes chunks by
// (r>>1)&3; read row = wm*128+mi*16+lr -> (row>>1)&3 == (lr>>1)&3. OK.
// Requires NT=K/32 >= 3, M%256==0, N%512==0, (gridDim.x*gridDim.y)%8==0.
__global__ __launch_bounds__(1024, 1)
void gemm256x512_bt(const u16* __restrict__ A, const u16* __restrict__ Bt,
                    const float* __restrict__ bias, u16* __restrict__ C,
                    int M, int N, int lda, int ldb, int K) {
    __shared__ __attribute__((aligned(16))) u16 sA[3 * 8192];    // [3][256*32] 48KB
    __shared__ __attribute__((aligned(16))) u16 sB[3 * 16384];   // [3][512*32] 96KB

    const int tid  = threadIdx.x;
    const int wid  = tid >> 6;          // 0..15
    const int lane = tid & 63;
    const int quad = lane >> 4;
    const int lr   = lane & 15;
    const int wm   = wid >> 3;          // 0..1
    const int wn   = wid & 7;           // 0..7

    // XCD-aware swizzle (nwg = 256, %8 == 0)
    const int NX = gridDim.x, NY = gridDim.y;
    const int bid = blockIdx.y * NX + blockIdx.x;
    const int xcd = bid & 7;
    const int j   = bid >> 3;
    const int yl  = j / NX;
    const int bx  = j - yl * NX;
    const int by  = xcd * (NY >> 3) + yl;
    const int m0 = by * 256;
    const int n0 = bx * 512;

    const int qsw   = (lr >> 1) & 3;
    const int row_s = tid >> 2;                            // 0..255
    const int lc    = ((tid & 3) ^ ((tid >> 3) & 3)) * 8;  // pre-swizzled src chunk

    const u16* Ast = A  + (size_t)(m0 + row_s) * lda + lc;
    const u16* Bst = Bt + (size_t)(n0 + row_s) * ldb + lc;

    const int rdA = (wm * 128 + lr) * 32 + ((quad ^ qsw) * 8);   // + mi*512
    const int rdB = (wn * 64  + lr) * 32 + ((quad ^ qsw) * 8);   // + ni*512
    const int d0  = tid * 8;

    const int NT = K >> 5;   // BK=32 tiles (>= 3)

    f32x4 acc[8][4] = {};
    bf16x8 av[4], bv[4];

#define STG_A1(bb, ko) async_cp16(Ast + (ko), &sA[(bb) * 8192 + d0])
#define STG_B1(bb, ko) async_cp16(Bst + (ko), &sB[(bb) * 16384 + d0])
#define STG_B2(bb, ko) async_cp16(Bst + (ko) + (size_t)256 * ldb, \
                                  &sB[(bb) * 16384 + 8192 + d0])
#define RD_A4X(bb, MO) do { _Pragma("unroll")                                  \
        for (int mi_ = 0; mi_ < 4; ++mi_)                                      \
            av[mi_] = *(const bf16x8*)&sA[(bb) * 8192 + rdA + ((MO) + mi_) * 512]; \
    } while (0)
#define RD_B4X(bb) do { _Pragma("unroll")                                      \
        for (int ni_ = 0; ni_ < 4; ++ni_)                                      \
            bv[ni_] = *(const bf16x8*)&sB[(bb) * 16384 + rdB + ni_ * 512];     \
    } while (0)
#define CLUSTER16(MO) do {                                                     \
        __builtin_amdgcn_s_barrier();                                          \
        asm volatile("s_waitcnt lgkmcnt(0)");                                  \
        __builtin_amdgcn_sched_barrier(0);                                     \
        __builtin_amdgcn_s_setprio(1);                                         \
        _Pragma("unroll")                                                      \
        for (int mi_ = 0; mi_ < 4; ++mi_)                                      \
            _Pragma("unroll")                                                  \
            for (int ni_ = 0; ni_ < 4; ++ni_)                                  \
                acc[(MO) + mi_][ni_] = __builtin_amdgcn_mfma_f32_16x16x32_bf16(\
                    av[mi_], bv[ni_], acc[(MO) + mi_][ni_], 0, 0, 0);          \
        __builtin_amdgcn_s_setprio(0);                                         \
    } while (0)

    // prologue: stage tiles 0 and 1 (6 loads); drain tile 0, keep tile 1
    STG_A1(0, 0);  STG_B1(0, 0);  STG_B2(0, 0);
    STG_A1(1, 32); STG_B1(1, 32); STG_B2(1, 32);
    asm volatile("s_waitcnt vmcnt(3)");
    __builtin_amdgcn_s_barrier();

    int cb = 0, sb = 2;
#pragma unroll 1
    for (int t = 0; t < NT - 2; ++t) {
        const size_t ko = (size_t)(t + 2) * 32;
        // ph0: A frags 0-3 + all B of tile t; stage A,B-half of t+2
        RD_A4X(cb, 0); RD_B4X(cb);
        STG_A1(sb, ko); STG_B1(sb, ko);
        CLUSTER16(0);
        __builtin_amdgcn_s_barrier();
        // ph1: A frags 4-7 (B reused); stage B-half2 of t+2; publish t+1
        RD_A4X(cb, 4);
        STG_B2(sb, ko);
        CLUSTER16(4);
        asm volatile("s_waitcnt vmcnt(3)");   // drain t+1's 3, keep t+2's 3
        __builtin_amdgcn_s_barrier();
        cb = (cb == 2) ? 0 : cb + 1;
        sb = (sb == 2) ? 0 : sb + 1;
    }
    // peeled tile NT-2: no staging; full drain publishes NT-1
    RD_A4X(cb, 0); RD_B4X(cb);
    CLUSTER16(0);
    __builtin_amdgcn_s_barrier();
    RD_A4X(cb, 4);
    CLUSTER16(4);
    asm volatile("s_waitcnt vmcnt(0)");
    __builtin_amdgcn_s_barrier();
    cb = (cb == 2) ? 0 : cb + 1;
    // peeled tile NT-1
    RD_A4X(cb, 0); RD_B4X(cb);
    CLUSTER16(0);
    __builtin_amdgcn_s_barrier();
    RD_A4X(cb, 4);
    CLUSTER16(4);

#undef CLUSTER16
#undef RD_B4X
#undef RD_A4X
#undef STG_B2
#undef STG_B1
#undef STG_A1

    // epilogue: D col = lane&15, row = quad*4 + reg
    float bvv[4];
#pragma unroll
    for (int ni = 0; ni < 4; ++ni)
        bvv[ni] = bias[n0 + wn * 64 + ni * 16 + lr];
#pragma unroll
    for (int mi = 0; mi < 8; ++mi) {
        const int mr = m0 + wm * 128 + mi * 16 + quad * 4;
#pragma unroll
        for (int r = 0; r < 4; ++r) {
            u16* Crow = C + (size_t)(mr + r) * N + n0 + wn * 64 + lr;
#pragma unroll
            for (int ni = 0; ni < 4; ++ni)
                Crow[ni * 16] = f2b(acc[mi][ni][r] + bvv[ni]);
        }
    }
}

// ---------- 256x256 bf16 GEMM partial (GEMM2 split-K), R3 16x16 structure ----------
// P[z][M,N] = A[M, z-slice of K] * Bt^T, bf16 partial out. 512 thr = 8 waves
// (2M x 4N), BK=64 as two k-halves, 4 phases/tile, counted vmcnt(4).
// Proven 0-conflict swizzle (R3).
__global__ __launch_bounds__(512, 2)
void gemm256_part(const u16* __restrict__ A, const u16* __restrict__ Bt,
                  u16* __restrict__ P, int M, int N, int lda, int ldb, int Ksl) {
    __shared__ __attribute__((aligned(16))) u16 sA[32768];  // [2 buf][2 kh][256*32]
    __shared__ __attribute__((aligned(16))) u16 sB[32768];

    const int tid  = threadIdx.x;
    const int wid  = tid >> 6;
    const int lane = tid & 63;
    const int quad = lane >> 4;
    const int lr   = lane & 15;
    const int wm   = wid >> 2;
    const int wn   = wid & 3;
    const int z    = blockIdx.z;

    const int NX = gridDim.x, NY = gridDim.y;
    const int bid = blockIdx.y * NX + blockIdx.x;
    const int xcd = bid & 7;
    const int j   = bid >> 3;
    const int yl  = j / NX;
    const int bx  = j - yl * NX;
    const int by  = xcd * (NY >> 3) + yl;
    const int m0 = by * 256;
    const int n0 = bx * 256;

    const int qsw   = (lr >> 1) & 3;
    const int row_s = tid >> 2;
    const int lc    = ((tid & 3) ^ ((tid >> 3) & 3)) * 8;

    const u16* Ast = A  + (size_t)z * Ksl + (size_t)(m0 + row_s) * lda + lc;
    const u16* Bst = Bt + (size_t)z * Ksl + (size_t)(n0 + row_s) * ldb + lc;

    const int rdA = (wm * 128 + lr) * 32 + ((quad ^ qsw) * 8);
    const int rdB = (wn * 64  + lr) * 32 + ((quad ^ qsw) * 8);
    const int d0  = tid * 8;

    const int NT = Ksl >> 6;

    f32x4 acc[8][4] = {};
    bf16x8 av[4], bv[4];

#define STG_A(hb, ko) do {                                                     \
        async_cp16(Ast + (ko),                      &sA[(hb) + d0]);           \
        async_cp16(Ast + (ko) + (size_t)128 * lda,  &sA[(hb) + d0 + 4096]);    \
    } while (0)
#define STG_B(hb, ko) do {                                                     \
        async_cp16(Bst + (ko),                      &sB[(hb) + d0]);           \
        async_cp16(Bst + (ko) + (size_t)128 * ldb,  &sB[(hb) + d0 + 4096]);    \
    } while (0)
#define RD_A4(hb, MO) do { _Pragma("unroll")                                   \
        for (int mi_ = 0; mi_ < 4; ++mi_)                                      \
            av[mi_] = *(const bf16x8*)&sA[(hb) + rdA + ((MO) + mi_) * 512];    \
    } while (0)
#define RD_B4(hb) do { _Pragma("unroll")                                       \
        for (int ni_ = 0; ni_ < 4; ++ni_)                                      \
            bv[ni_] = *(const bf16x8*)&sB[(hb) + rdB + ni_ * 512];             \
    } while (0)
#define SYNC_MFMA16(MO) do {                                                   \
        __builtin_amdgcn_s_barrier();                                          \
        asm volatile("s_waitcnt lgkmcnt(0)");                                  \
        __builtin_amdgcn_sched_barrier(0);                                     \
        __builtin_amdgcn_s_setprio(1);                                         \
        _Pragma("unroll")                                                      \
        for (int mi_ = 0; mi_ < 4; ++mi_)                                      \
            _Pragma("unroll")                                                  \
            for (int ni_ = 0; ni_ < 4; ++ni_)                                  \
                acc[(MO) + mi_][ni_] = __builtin_amdgcn_mfma_f32_16x16x32_bf16(\
                    av[mi_], bv[ni_], acc[(MO) + mi_][ni_], 0, 0, 0);          \
        __builtin_amdgcn_s_setprio(0);                                         \
    } while (0)

    STG_A(0, 0);      STG_B(0, 0);
    STG_A(8192, 32);  STG_B(8192, 32);
    asm volatile("s_waitcnt vmcnt(4)");
    __builtin_amdgcn_s_barrier();

#pragma unroll 1
    for (int t = 0; t < NT - 1; ++t) {
        const int cb = (t & 1) << 14;
        const int nb = cb ^ 16384;
        const size_t kt = (size_t)(t + 1) * 64;
        RD_A4(cb, 0); RD_B4(cb);
        STG_A(nb, kt);
        SYNC_MFMA16(0);
        __builtin_amdgcn_s_barrier();
        RD_A4(cb, 4);
        STG_B(nb, kt);
        SYNC_MFMA16(4);
        asm volatile("s_waitcnt vmcnt(4)");
        __builtin_amdgcn_s_barrier();
        RD_A4(cb + 8192, 0); RD_B4(cb + 8192);
        STG_A(nb + 8192, kt + 32);
        SYNC_MFMA16(0);
        __builtin_amdgcn_s_barrier();
        RD_A4(cb + 8192, 4);
        STG_B(nb + 8192, kt + 32);
        SYNC_MFMA16(4);
        asm volatile("s_waitcnt vmcnt(4)");
        __builtin_amdgcn_s_barrier();
    }
    {
        const int cb = ((NT - 1) & 1) << 14;
        RD_A4(cb, 0); RD_B4(cb);
        SYNC_MFMA16(0);
        __builtin_amdgcn_s_barrier();
        RD_A4(cb, 4);
        SYNC_MFMA16(4);
        asm volatile("s_waitcnt vmcnt(0)");
        __builtin_amdgcn_s_barrier();
        RD_A4(cb + 8192, 0); RD_B4(cb + 8192);
        SYNC_MFMA16(0);
        __builtin_amdgcn_s_barrier();
        RD_A4(cb + 8192, 4);
        SYNC_MFMA16(4);
    }
#undef SYNC_MFMA16
#undef RD_B4
#undef RD_A4
#undef STG_B
#undef STG_A

    u16* Pb = P + (size_t)z * ((size_t)M * N);
#pragma unroll
    for (int mi = 0; mi < 8; ++mi) {
        const int mr = m0 + wm * 128 + mi * 16 + quad * 4;
#pragma unroll
        for (int r = 0; r < 4; ++r) {
            u16* Prow = Pb + (size_t)(mr + r) * N + n0 + wn * 64 + lr;
#pragma unroll
            for (int ni = 0; ni < 4; ++ni)
                Prow[ni * 16] = f2b(acc[mi][ni][r]);
        }
    }
}

// ---------- bf16 GEMM 128x128 (fallback for GEMM2 if ws too small) ----------
__global__ __launch_bounds__(256)
void gemm_bt_bias(const u16* __restrict__ A, const u16* __restrict__ Bt,
                  const float* __restrict__ bias, u16* __restrict__ C,
                  int M, int N, int K) {
    __shared__ __attribute__((aligned(16))) u16 sA[2][128 * 32];
    __shared__ __attribute__((aligned(16))) u16 sB[2][128 * 32];

    const int tid  = threadIdx.x;
    const int wid  = tid >> 6;
    const int lane = tid & 63;
    const int quad = lane >> 4;
    const int lr   = lane & 15;
    const int wm   = wid & 1;
    const int wn   = wid >> 1;

    const int NX = gridDim.x, NY = gridDim.y;
    const int bid = blockIdx.y * NX + blockIdx.x;
    const int xcd = bid & 7;
    const int j   = bid >> 3;
    const int yl  = j / NX;
    const int bx  = j - yl * NX;
    const int by  = xcd * (NY >> 3) + yl;

    const int m0 = by * 128;
    const int n0 = bx * 128;

    const int sr  = lane >> 2;
    const int scl = ((lane & 3) ^ ((lane >> 3) & 3)) * 8;
    const int qsw = (lr >> 1) & 3;

    const u16* Ag = A + (size_t)m0 * K;
    const u16* Bg = Bt + (size_t)n0 * K;

    f32x4 acc[4][4] = {};

    for (int k0 = 0; k0 < K; k0 += 64) {
#pragma unroll
        for (int s = 0; s < 2; ++s) {
#pragma unroll
            for (int i = 0; i < 2; ++i) {
                const int rb = wid * 32 + i * 16;
                async_cp16(Ag + (size_t)(rb + sr) * K + k0 + s * 32 + scl,
                           &sA[s][rb * 32]);
                async_cp16(Bg + (size_t)(rb + sr) * K + k0 + s * 32 + scl,
                           &sB[s][rb * 32]);
            }
        }
        __syncthreads();

#pragma unroll
        for (int s = 0; s < 2; ++s) {
            bf16x8 af[4], bfr[4];
#pragma unroll
            for (int mi = 0; mi < 4; ++mi)
                af[mi] = *(const bf16x8*)
                    &sA[s][(wm * 64 + mi * 16 + lr) * 32 + ((quad ^ qsw) * 8)];
#pragma unroll
            for (int ni = 0; ni < 4; ++ni)
                bfr[ni] = *(const bf16x8*)
                    &sB[s][(wn * 64 + ni * 16 + lr) * 32 + ((quad ^ qsw) * 8)];

#pragma unroll
            for (int mi = 0; mi < 4; ++mi)
#pragma unroll
                for (int ni = 0; ni < 4; ++ni)
                    acc[mi][ni] = __builtin_amdgcn_mfma_f32_16x16x32_bf16(
                        af[mi], bfr[ni], acc[mi][ni], 0, 0, 0);
        }

        __syncthreads();
    }

    float bvv[4];
#pragma unroll
    for (int ni = 0; ni < 4; ++ni)
        bvv[ni] = bias[n0 + wn * 64 + ni * 16 + lr];

#pragma unroll
    for (int mi = 0; mi < 4; ++mi) {
        const int mr = m0 + wm * 64 + mi * 16 + quad * 4;
#pragma unroll
        for (int r = 0; r < 4; ++r) {
            u16* Crow = C + (size_t)(mr + r) * N + n0 + wn * 64 + lr;
#pragma unroll
            for (int ni = 0; ni < 4; ++ni)
                Crow[ni * 16] = f2b(acc[mi][ni][r] + bvv[ni]);
        }
    }
}

// ---------- fused LN(4096) + GELU, in-place on bf16 h ----------
__global__ __launch_bounds__(256)
void ln_gelu_hid(u16* __restrict__ h, const float* __restrict__ g,
                 const float* __restrict__ be) {
    __shared__ float red[8];
    const int row = blockIdx.x;
    u16* hp = h + (size_t)row * HID_DIM;
    const int t = threadIdx.x;

    uint4 v0 = *(const uint4*)&hp[t * 8];
    uint4 v1 = *(const uint4*)&hp[(t + 256) * 8];

    float vals[16];
    {
        const uint32_t w0[4] = {v0.x, v0.y, v0.z, v0.w};
        const uint32_t w1[4] = {v1.x, v1.y, v1.z, v1.w};
#pragma unroll
        for (int q = 0; q < 4; ++q) {
            vals[q * 2]     = b2f((u16)(w0[q] & 0xffffu));
            vals[q * 2 + 1] = b2f((u16)(w0[q] >> 16));
            vals[8 + q * 2]     = b2f((u16)(w1[q] & 0xffffu));
            vals[8 + q * 2 + 1] = b2f((u16)(w1[q] >> 16));
        }
    }
    float s = 0.f, ss = 0.f;
#pragma unroll
    for (int i = 0; i < 16; ++i) { s += vals[i]; ss += vals[i] * vals[i]; }

    float4 gv[4], bv[4];
    gv[0] = *(const float4*)&g[t * 8];
    gv[1] = *(const float4*)&g[t * 8 + 4];
    gv[2] = *(const float4*)&g[(t + 256) * 8];
    gv[3] = *(const float4*)&g[(t + 256) * 8 + 4];
    bv[0] = *(const float4*)&be[t * 8];
    bv[1] = *(const float4*)&be[t * 8 + 4];
    bv[2] = *(const float4*)&be[(t + 256) * 8];
    bv[3] = *(const float4*)&be[(t + 256) * 8 + 4];

#pragma unroll
    for (int off = 32; off > 0; off >>= 1) {
        s += __shfl_down(s, off, 64);
        ss += __shfl_down(ss, off, 64);
    }
    if ((t & 63) == 0) { red[(t >> 6) * 2] = s; red[(t >> 6) * 2 + 1] = ss; }
    __syncthreads();
    s  = red[0] + red[2] + red[4] + red[6];
    ss = red[1] + red[3] + red[5] + red[7];
    const float mean = s * (1.f / HID_DIM);
    const float rstd = rsqrtf(ss * (1.f / HID_DIM) - mean * mean + 1e-5f);

    const float* gf = (const float*)gv;
    const float* bf = (const float*)bv;
#pragma unroll
    for (int j = 0; j < 2; ++j) {
        uint4 o;
        uint32_t* ow = (uint32_t*)&o;
#pragma unroll
        for (int q = 0; q < 4; ++q) {
            const int k = j * 8 + q * 2;
            float u0 = gelu_fast((vals[k]     - mean) * rstd * gf[k]     + bf[k]);
            float u1 = gelu_fast((vals[k + 1] - mean) * rstd * gf[k + 1] + bf[k + 1]);
            ow[q] = (uint32_t)f2b(u0) | ((uint32_t)f2b(u1) << 16);
        }
        *(uint4*)&hp[(t + j * 256) * 8] = o;
    }
}

// ---------- fused LN(1024) + GELU + weighted accumulate (bf16 y path) ----------
__global__ __launch_bounds__(256)
void ln_gelu_combine(const u16* __restrict__ y, const float* __restrict__ g,
                     const float* __restrict__ be, const float* __restrict__ wts,
                     float* __restrict__ out, int e, int first) {
    __shared__ float red[8];
    const int row = blockIdx.x;
    const u16* yp = y + (size_t)row * OUT_DIM;
    const int t = threadIdx.x;

    uint2 v = *(const uint2*)&yp[t * 4];
    float f0 = b2f((u16)(v.x & 0xffffu)), f1 = b2f((u16)(v.x >> 16));
    float f2 = b2f((u16)(v.y & 0xffffu)), f3 = b2f((u16)(v.y >> 16));
    float s = f0 + f1 + f2 + f3;
    float ss = f0 * f0 + f1 * f1 + f2 * f2 + f3 * f3;

    const int n = t * 4;
    float4 gv = *(const float4*)&g[n];
    float4 bvv = *(const float4*)&be[n];

#pragma unroll
    for (int off = 32; off > 0; off >>= 1) {
        s += __shfl_down(s, off, 64);
        ss += __shfl_down(ss, off, 64);
    }
    if ((t & 63) == 0) { red[(t >> 6) * 2] = s; red[(t >> 6) * 2 + 1] = ss; }
    __syncthreads();
    s  = red[0] + red[2] + red[4] + red[6];
    ss = red[1] + red[3] + red[5] + red[7];
    const float mean = s * (1.f / OUT_DIM);
    const float rstd = rsqrtf(ss * (1.f / OUT_DIM) - mean * mean + 1e-5f);

    const float w = wts[(size_t)row * NEXP + e];
    float4 o;
    if (first) { o.x = o.y = o.z = o.w = 0.f; }
    else       { o = *(const float4*)&out[(size_t)row * OUT_DIM + n]; }
    o.x += w * gelu_fast((f0 - mean) * rstd * gv.x + bvv.x);
    o.y += w * gelu_fast((f1 - mean) * rstd * gv.y + bvv.y);
    o.z += w * gelu_fast((f2 - mean) * rstd * gv.z + bvv.z);
    o.w += w * gelu_fast((f3 - mean) * rstd * gv.w + bvv.w);
    *(float4*)&out[(size_t)row * OUT_DIM + n] = o;
}

// ---------- split-K combine: y = p0+p1+b2 (bf16 partials), LN+GELU+acc ----------
__global__ __launch_bounds__(256)
void ln_gelu_combine_2bf(const u16* __restrict__ P, const float* __restrict__ g,
                         const float* __restrict__ be, const float* __restrict__ bs,
                         const float* __restrict__ wts, float* __restrict__ out,
                         int e, int first) {
    __shared__ float red[8];
    const int row = blockIdx.x;
    const int t = threadIdx.x;
    const int n = t * 4;

    const u16* p0 = P + (size_t)row * OUT_DIM + n;
    const u16* p1 = p0 + (size_t)B_DIM * OUT_DIM;
    uint2 a = *(const uint2*)p0;
    uint2 b = *(const uint2*)p1;
    float4 c  = *(const float4*)&bs[n];
    float f0 = b2f((u16)(a.x & 0xffffu)) + b2f((u16)(b.x & 0xffffu)) + c.x;
    float f1 = b2f((u16)(a.x >> 16))     + b2f((u16)(b.x >> 16))     + c.y;
    float f2 = b2f((u16)(a.y & 0xffffu)) + b2f((u16)(b.y & 0xffffu)) + c.z;
    float f3 = b2f((u16)(a.y >> 16))     + b2f((u16)(b.y >> 16))     + c.w;
    float s = f0 + f1 + f2 + f3;
    float ss = f0 * f0 + f1 * f1 + f2 * f2 + f3 * f3;

    float4 gv = *(const float4*)&g[n];
    float4 bvv = *(const float4*)&be[n];

#pragma unroll
    for (int off = 32; off > 0; off >>= 1) {
        s += __shfl_down(s, off, 64);
        ss += __shfl_down(ss, off, 64);
    }
    if ((t & 63) == 0) { red[(t >> 6) * 2] = s; red[(t >> 6) * 2 + 1] = ss; }
    __syncthreads();
    s  = red[0] + red[2] + red[4] + red[6];
    ss = red[1] + red[3] + red[5] + red[7];
    const float mean = s * (1.f / OUT_DIM);
    const float rstd = rsqrtf(ss * (1.f / OUT_DIM) - mean * mean + 1e-5f);

    const float w = wts[(size_t)row * NEXP + e];
    float4 o;
    if (first) { o.x = o.y = o.z = o.w = 0.f; }
    else       { o = *(const float4*)&out[(size_t)row * OUT_DIM + n]; }
    o.x += w * gelu_fast((f0 - mean) * rstd * gv.x + bvv.x);
    o.y += w * gelu_fast((f1 - mean) * rstd * gv.y + bvv.y);
    o.z += w * gelu_fast((f2 - mean) * rstd * gv.z + bvv.z);
    o.w += w * gelu_fast((f3 - mean) * rstd * gv.w + bvv.w);
    *(float4*)&out[(size_t)row * OUT_DIM + n] = o;
}

// ---------- launch ----------
extern "C" void kernel_launch(void* const* d_in, const int* in_sizes, int n_in,
                              void* d_out, int out_size, void* d_ws, size_t ws_size,
                              hipStream_t stream) {
    (void)in_sizes; (void)n_in; (void)out_size;
    const float* x   = (const float*)d_in[0];  // [8192,1024]
    const float* wts = (const float*)d_in[1];  // [8192,8]
    const float* W1  = (const float*)d_in[2];  // [8,1024,4096]
    const float* b1  = (const float*)d_in[3];  // [8,4096]
    const float* g1  = (const float*)d_in[4];  // [8,4096]
    const float* be1 = (const float*)d_in[5];  // [8,4096]
    const float* W2  = (const float*)d_in[6];  // [8,4096,1024]
    const float* b2  = (const float*)d_in[7];  // [8,1024]
    const float* g2  = (const float*)d_in[8];  // [8,1024]
    const float* be2 = (const float*)d_in[9];  // [8,1024]
    float* out = (float*)d_out;                // [8192,1024]

    // workspace carve: xb 16MB | w1t 8MB | w2t 8MB | h 64MB | P 32MB (bf16 x2)
    char* p = (char*)d_ws;
    u16* xb  = (u16*)p; p += (size_t)B_DIM * IN_DIM * 2;
    u16* w1t = (u16*)p; p += (size_t)HID_DIM * IN_DIM * 2;
    u16* w2t = (u16*)p; p += (size_t)OUT_DIM * HID_DIM * 2;
    u16* h   = (u16*)p; p += (size_t)B_DIM * HID_DIM * 2;
    u16* P   = (u16*)p;                        // split path: 2 x 16MB bf16 partials
    u16* y   = (u16*)p;                        // fallback path: 16MB bf16

    const size_t need = (size_t)B_DIM * IN_DIM * 2 + (size_t)HID_DIM * IN_DIM * 2 +
                        (size_t)OUT_DIM * HID_DIM * 2 + (size_t)B_DIM * HID_DIM * 2 +
                        (size_t)2 * B_DIM * OUT_DIM * 2;   // 128 MB
    const int splitk = (ws_size >= need) ? 1 : 0;

    cvt_bf16<<<(B_DIM * IN_DIM / 4 + 255) / 256, 256, 0, stream>>>(x, xb, B_DIM * IN_DIM / 4);

    for (int e = 0; e < NEXP; ++e) {
        transpose_cvt2<<<dim3(HID_DIM / 32, IN_DIM / 32, 2), 256, 0, stream>>>(
            W1 + (size_t)e * IN_DIM * HID_DIM, w1t,
            W2 + (size_t)e * HID_DIM * OUT_DIM, w2t);
        // h = xb @ W1[e] + b1[e]   (M=8192, N=4096, K=1024) — 256x512 staging-min
        gemm256x512_bt<<<dim3(HID_DIM / 512, B_DIM / 256), 1024, 0, stream>>>(
            xb, w1t, b1 + (size_t)e * HID_DIM, h, B_DIM, HID_DIM, IN_DIM, IN_DIM, IN_DIM);
        // h = gelu(ln(h))
        ln_gelu_hid<<<B_DIM, 256, 0, stream>>>(h, g1 + (size_t)e * HID_DIM,
                                               be1 + (size_t)e * HID_DIM);
        if (splitk) {
            // P[s] = h @ W2[e] (K-slice s of 2048), bf16 partials; 256 blocks
            gemm256_part<<<dim3(OUT_DIM / 256, B_DIM / 256, 2), 512, 0, stream>>>(
                h, w2t, P, B_DIM, OUT_DIM, HID_DIM, HID_DIM, HID_DIM / 2);
            // out (+)= wts[:,e] * gelu(ln(p0+p1+b2))
            ln_gelu_combine_2bf<<<B_DIM, 256, 0, stream>>>(
                P, g2 + (size_t)e * OUT_DIM, be2 + (size_t)e * OUT_DIM,
                b2 + (size_t)e * OUT_DIM, wts, out, e, e == 0 ? 1 : 0);
        } else {
            // fallback: 128^2 GEMM2 + bf16 combine
            gemm_bt_bias<<<dim3(OUT_DIM / 128, B_DIM / 128), 256, 0, stream>>>(
                h, w2t, b2 + (size_t)e * OUT_DIM, y, B_DIM, OUT_DIM, HID_DIM);
            ln_gelu_combine<<<B_DIM, 256, 0, stream>>>(y, g2 + (size_t)e * OUT_DIM,
                                                       be2 + (size_t)e * OUT_DIM, wts, out,
                                                       e, e == 0 ? 1 : 0);
        }
    }
}

// Round 6
// 1882.929 us; speedup vs baseline: 2.9375x; 2.9375x over previous
//
#include <hip/hip_runtime.h>
#include <cstdint>
#include <cstddef>

typedef unsigned short u16;
typedef float f32x4 __attribute__((ext_vector_type(4)));
typedef __bf16 bf16x8 __attribute__((ext_vector_type(8)));

#define B_DIM   8192
#define IN_DIM  1024
#define HID_DIM 4096
#define OUT_DIM 1024
#define NEXP    8

// ---------- helpers ----------
__device__ __forceinline__ u16 f2b(float f) {
    uint32_t u = __builtin_bit_cast(uint32_t, f);
    u += 0x7fffu + ((u >> 16) & 1u);      // RNE
    return (u16)(u >> 16);
}
__device__ __forceinline__ float b2f(u16 b) {
    uint32_t u = ((uint32_t)b) << 16;
    return __builtin_bit_cast(float, u);
}
// tanh-form GELU via one v_exp_f32: gelu(x) = x * e/(e+1), e = exp(2*y).
__device__ __forceinline__ float gelu_fast(float x) {
    float y = x * (0.7978845608f + 0.03567740814f * x * x);
    float a = fminf(y * 2.8853900818f, 80.0f);     // 2*log2(e)*y, clamp overflow
    float e = __builtin_amdgcn_exp2f(a);
    return x * e * __builtin_amdgcn_rcpf(e + 1.0f);
}
__device__ __forceinline__ void async_cp16(const void* g, void* l) {
    __builtin_amdgcn_global_load_lds(
        (const __attribute__((address_space(1))) void*)g,
        (__attribute__((address_space(3))) void*)l,
        16, 0, 0);
}

// ---------- fp32 -> bf16 convert ----------
__global__ __launch_bounds__(256)
void cvt_bf16(const float* __restrict__ in, u16* __restrict__ out, int n4) {
    int i = blockIdx.x * 256 + threadIdx.x;
    if (i >= n4) return;
    float4 v = *(const float4*)&in[(size_t)i * 4];
    uint2 o;
    o.x = (uint32_t)f2b(v.x) | ((uint32_t)f2b(v.y) << 16);
    o.y = (uint32_t)f2b(v.z) | ((uint32_t)f2b(v.w) << 16);
    *(uint2*)&out[(size_t)i * 4] = o;
}

// ---------- transpose both expert weights: [K,N] fp32 -> [N,K] bf16 ----------
__global__ __launch_bounds__(256)
void transpose_cvt2(const float* __restrict__ W1e, u16* __restrict__ w1t,
                    const float* __restrict__ W2e, u16* __restrict__ w2t) {
    __shared__ float tile[32][33];
    const float* W; u16* Wt; int K, N, n0, k0;
    if (blockIdx.z == 0) {
        W = W1e; Wt = w1t; K = IN_DIM; N = HID_DIM;
        n0 = blockIdx.x * 32; k0 = blockIdx.y * 32;
    } else {
        W = W2e; Wt = w2t; K = HID_DIM; N = OUT_DIM;
        n0 = blockIdx.y * 32; k0 = blockIdx.x * 32;
    }
    const int tx = threadIdx.x & 31, ty = threadIdx.x >> 5;   // ty 0..7
#pragma unroll
    for (int i = 0; i < 4; ++i) {
        int k = k0 + ty + i * 8;
        tile[ty + i * 8][tx] = W[(size_t)k * N + n0 + tx];
    }
    __syncthreads();
#pragma unroll
    for (int i = 0; i < 4; ++i) {
        int n = n0 + ty + i * 8;
        Wt[(size_t)n * K + k0 + tx] = f2b(tile[tx][ty + i * 8]);
    }
}

// ---------- 256x256 bf16 GEMM, 8-phase schedule (R3-verified structure) ----------
// C = A[M,K(lda)] * Bt[N,K(ldb)]^T. PARTIAL=0: +bias, bf16 out.
// PARTIAL=1: bf16 partial out at z*M*N (split-K via blockIdx.z, depth Ksl).
// 512 thr = 8 waves (2M x 4N), per-wave 128x64 (acc[8][4] = 128 acc regs;
// NOTE R5 lesson: this acc footprint + 512 threads is the register-file
// ceiling — do NOT grow the block to 1024 threads, it spills to scratch).
// BK=64 staged as two k-halves of 256x32. 4 phases/K-tile, each
// { 4-8 ds_read_b128 || stage 1 k-half (2 global_load_lds) -> s_barrier ->
// lgkmcnt(0) -> sched_barrier(0) -> setprio(1) -> 16 MFMA -> setprio(0) }.
// Counted vmcnt(4) only at ph1/ph3. 2-buffer LDS (128 KiB, 1 block/CU).
// Swizzle: stage chunk lc=((tid&3)^((tid>>3)&3))*8, read chunk
// (quad^((lr>>1)&3)) — measured 0 bank conflicts (R2/R3).
// Requires NT=Ksl/64 >= 2, N%256==0, M%256==0, gridDim.y % 8 == 0.
template<int PARTIAL>
__global__ __launch_bounds__(512, 2)
void gemm256_8ph(const u16* __restrict__ A, const u16* __restrict__ Bt,
                 const float* __restrict__ bias, u16* __restrict__ C,
                 int M, int N, int lda, int ldb, int Ksl) {
    __shared__ __attribute__((aligned(16))) u16 sA[32768];  // [2 buf][2 kh][256*32]
    __shared__ __attribute__((aligned(16))) u16 sB[32768];

    const int tid  = threadIdx.x;
    const int wid  = tid >> 6;
    const int lane = tid & 63;
    const int quad = lane >> 4;
    const int lr   = lane & 15;
    const int wm   = wid >> 2;        // 0..1
    const int wn   = wid & 3;         // 0..3
    const int z    = blockIdx.z;      // K-slice (split-K); 0 otherwise

    // XCD-aware supertile swizzle (NY multiple of 8).
    const int NX = gridDim.x, NY = gridDim.y;
    const int bid = blockIdx.y * NX + blockIdx.x;
    const int xcd = bid & 7;
    const int j   = bid >> 3;
    const int yl  = j / NX;
    const int bx  = j - yl * NX;
    const int by  = xcd * (NY >> 3) + yl;
    const int m0 = by * 256;
    const int n0 = bx * 256;

    const int qsw   = (lr >> 1) & 3;                       // read-side XOR
    const int row_s = tid >> 2;                            // 0..127 staging row
    const int lc    = ((tid & 3) ^ ((tid >> 3) & 3)) * 8;  // pre-swizzled src chunk

    const u16* Ast = A  + (size_t)z * Ksl + (size_t)(m0 + row_s) * lda + lc;
    const u16* Bst = Bt + (size_t)z * Ksl + (size_t)(n0 + row_s) * ldb + lc;

    const int rdA = (wm * 128 + lr) * 32 + ((quad ^ qsw) * 8);
    const int rdB = (wn * 64  + lr) * 32 + ((quad ^ qsw) * 8);
    const int d0  = tid * 8;          // staging dest within a k-half

    const int NT = Ksl >> 6;          // BK=64 tiles (>= 2)

    f32x4 acc[8][4] = {};
    bf16x8 av[4], bv[4];

#define STG_A(hb, ko) do {                                                     \
        async_cp16(Ast + (ko),                      &sA[(hb) + d0]);           \
        async_cp16(Ast + (ko) + (size_t)128 * lda,  &sA[(hb) + d0 + 4096]);    \
    } while (0)
#define STG_B(hb, ko) do {                                                     \
        async_cp16(Bst + (ko),                      &sB[(hb) + d0]);           \
        async_cp16(Bst + (ko) + (size_t)128 * ldb,  &sB[(hb) + d0 + 4096]);    \
    } while (0)
#define RD_A4(hb, MO) do { _Pragma("unroll")                                   \
        for (int mi_ = 0; mi_ < 4; ++mi_)                                      \
            av[mi_] = *(const bf16x8*)&sA[(hb) + rdA + ((MO) + mi_) * 512];    \
    } while (0)
#define RD_B4(hb) do { _Pragma("unroll")                                       \
        for (int ni_ = 0; ni_ < 4; ++ni_)                                      \
            bv[ni_] = *(const bf16x8*)&sB[(hb) + rdB + ni_ * 512];             \
    } while (0)
#define SYNC_MFMA16(MO) do {                                                   \
        __builtin_amdgcn_s_barrier();                                          \
        asm volatile("s_waitcnt lgkmcnt(0)");                                  \
        __builtin_amdgcn_sched_barrier(0);                                     \
        __builtin_amdgcn_s_setprio(1);                                         \
        _Pragma("unroll")                                                      \
        for (int mi_ = 0; mi_ < 4; ++mi_)                                      \
            _Pragma("unroll")                                                  \
            for (int ni_ = 0; ni_ < 4; ++ni_)                                  \
                acc[(MO) + mi_][ni_] = __builtin_amdgcn_mfma_f32_16x16x32_bf16(\
                    av[mi_], bv[ni_], acc[(MO) + mi_][ni_], 0, 0, 0);          \
        __builtin_amdgcn_s_setprio(0);                                         \
    } while (0)

    // prologue: stage tile 0 fully (Ak0,Bk0,Ak1,Bk1); publish k-half 0
    STG_A(0, 0);      STG_B(0, 0);
    STG_A(8192, 32);  STG_B(8192, 32);
    asm volatile("s_waitcnt vmcnt(4)");
    __builtin_amdgcn_s_barrier();

#pragma unroll 1
    for (int t = 0; t < NT - 1; ++t) {
        const int cb = (t & 1) << 14;          // current buf base (0 / 16384)
        const int nb = cb ^ 16384;             // next buf base
        const size_t kt = (size_t)(t + 1) * 64;
        // ph0: kh0, mi 0-3 (+all B kh0); stage Ak0(t+1)
        RD_A4(cb, 0); RD_B4(cb);
        STG_A(nb, kt);
        SYNC_MFMA16(0);
        __builtin_amdgcn_s_barrier();
        // ph1: kh0, mi 4-7 (B reused); stage Bk0(t+1); publish kh1(t)
        RD_A4(cb, 4);
        STG_B(nb, kt);
        SYNC_MFMA16(4);
        asm volatile("s_waitcnt vmcnt(4)");
        __builtin_amdgcn_s_barrier();
        // ph2: kh1, mi 0-3 (+all B kh1); stage Ak1(t+1)
        RD_A4(cb + 8192, 0); RD_B4(cb + 8192);
        STG_A(nb + 8192, kt + 32);
        SYNC_MFMA16(0);
        __builtin_amdgcn_s_barrier();
        // ph3: kh1, mi 4-7; stage Bk1(t+1); publish kh0(t+1)
        RD_A4(cb + 8192, 4);
        STG_B(nb + 8192, kt + 32);
        SYNC_MFMA16(4);
        asm volatile("s_waitcnt vmcnt(4)");
        __builtin_amdgcn_s_barrier();
    }
    {   // peeled last tile: no staging, exact drains
        const int cb = ((NT - 1) & 1) << 14;
        RD_A4(cb, 0); RD_B4(cb);
        SYNC_MFMA16(0);
        __builtin_amdgcn_s_barrier();
        RD_A4(cb, 4);
        SYNC_MFMA16(4);
        asm volatile("s_waitcnt vmcnt(0)");    // publish kh1 of last tile
        __builtin_amdgcn_s_barrier();
        RD_A4(cb + 8192, 0); RD_B4(cb + 8192);
        SYNC_MFMA16(0);
        __builtin_amdgcn_s_barrier();
        RD_A4(cb + 8192, 4);
        SYNC_MFMA16(4);
    }
#undef SYNC_MFMA16
#undef RD_B4
#undef RD_A4
#undef STG_B
#undef STG_A

    // epilogue: D col = lane&15, row = quad*4 + reg
    if constexpr (PARTIAL) {
        u16* Pb = C + (size_t)z * ((size_t)M * N);
#pragma unroll
        for (int mi = 0; mi < 8; ++mi) {
            const int mr = m0 + wm * 128 + mi * 16 + quad * 4;
#pragma unroll
            for (int r = 0; r < 4; ++r) {
                u16* Prow = Pb + (size_t)(mr + r) * N + n0 + wn * 64 + lr;
#pragma unroll
                for (int ni = 0; ni < 4; ++ni)
                    Prow[ni * 16] = f2b(acc[mi][ni][r]);
            }
        }
    } else {
        float bvv[4];
#pragma unroll
        for (int ni = 0; ni < 4; ++ni)
            bvv[ni] = bias[n0 + wn * 64 + ni * 16 + lr];
#pragma unroll
        for (int mi = 0; mi < 8; ++mi) {
            const int mr = m0 + wm * 128 + mi * 16 + quad * 4;
#pragma unroll
            for (int r = 0; r < 4; ++r) {
                u16* Crow = C + (size_t)(mr + r) * N + n0 + wn * 64 + lr;
#pragma unroll
                for (int ni = 0; ni < 4; ++ni)
                    Crow[ni * 16] = f2b(acc[mi][ni][r] + bvv[ni]);
            }
        }
    }
}

// ---------- bf16 GEMM 128x128 (fallback for GEMM2 if ws too small) ----------
__global__ __launch_bounds__(256)
void gemm_bt_bias(const u16* __restrict__ A, const u16* __restrict__ Bt,
                  const float* __restrict__ bias, u16* __restrict__ C,
                  int M, int N, int K) {
    __shared__ __attribute__((aligned(16))) u16 sA[2][128 * 32];
    __shared__ __attribute__((aligned(16))) u16 sB[2][128 * 32];

    const int tid  = threadIdx.x;
    const int wid  = tid >> 6;
    const int lane = tid & 63;
    const int quad = lane >> 4;
    const int lr   = lane & 15;
    const int wm   = wid & 1;
    const int wn   = wid >> 1;

    const int NX = gridDim.x, NY = gridDim.y;
    const int bid = blockIdx.y * NX + blockIdx.x;
    const int xcd = bid & 7;
    const int j   = bid >> 3;
    const int yl  = j / NX;
    const int bx  = j - yl * NX;
    const int by  = xcd * (NY >> 3) + yl;

    const int m0 = by * 128;
    const int n0 = bx * 128;

    const int sr  = lane >> 2;
    const int scl = ((lane & 3) ^ ((lane >> 3) & 3)) * 8;
    const int qsw = (lr >> 1) & 3;

    const u16* Ag = A + (size_t)m0 * K;
    const u16* Bg = Bt + (size_t)n0 * K;

    f32x4 acc[4][4] = {};

    for (int k0 = 0; k0 < K; k0 += 64) {
#pragma unroll
        for (int s = 0; s < 2; ++s) {
#pragma unroll
            for (int i = 0; i < 2; ++i) {
                const int rb = wid * 32 + i * 16;
                async_cp16(Ag + (size_t)(rb + sr) * K + k0 + s * 32 + scl,
                           &sA[s][rb * 32]);
                async_cp16(Bg + (size_t)(rb + sr) * K + k0 + s * 32 + scl,
                           &sB[s][rb * 32]);
            }
        }
        __syncthreads();

#pragma unroll
        for (int s = 0; s < 2; ++s) {
            bf16x8 af[4], bfr[4];
#pragma unroll
            for (int mi = 0; mi < 4; ++mi)
                af[mi] = *(const bf16x8*)
                    &sA[s][(wm * 64 + mi * 16 + lr) * 32 + ((quad ^ qsw) * 8)];
#pragma unroll
            for (int ni = 0; ni < 4; ++ni)
                bfr[ni] = *(const bf16x8*)
                    &sB[s][(wn * 64 + ni * 16 + lr) * 32 + ((quad ^ qsw) * 8)];

#pragma unroll
            for (int mi = 0; mi < 4; ++mi)
#pragma unroll
                for (int ni = 0; ni < 4; ++ni)
                    acc[mi][ni] = __builtin_amdgcn_mfma_f32_16x16x32_bf16(
                        af[mi], bfr[ni], acc[mi][ni], 0, 0, 0);
        }

        __syncthreads();
    }

    float bvv[4];
#pragma unroll
    for (int ni = 0; ni < 4; ++ni)
        bvv[ni] = bias[n0 + wn * 64 + ni * 16 + lr];

#pragma unroll
    for (int mi = 0; mi < 4; ++mi) {
        const int mr = m0 + wm * 64 + mi * 16 + quad * 4;
#pragma unroll
        for (int r = 0; r < 4; ++r) {
            u16* Crow = C + (size_t)(mr + r) * N + n0 + wn * 64 + lr;
#pragma unroll
            for (int ni = 0; ni < 4; ++ni)
                Crow[ni * 16] = f2b(acc[mi][ni][r] + bvv[ni]);
        }
    }
}

// ---------- fused LN(4096) + GELU, in-place on bf16 h ----------
__global__ __launch_bounds__(256)
void ln_gelu_hid(u16* __restrict__ h, const float* __restrict__ g,
                 const float* __restrict__ be) {
    __shared__ float red[8];
    const int row = blockIdx.x;
    u16* hp = h + (size_t)row * HID_DIM;
    const int t = threadIdx.x;

    uint4 v0 = *(const uint4*)&hp[t * 8];
    uint4 v1 = *(const uint4*)&hp[(t + 256) * 8];

    float vals[16];
    {
        const uint32_t w0[4] = {v0.x, v0.y, v0.z, v0.w};
        const uint32_t w1[4] = {v1.x, v1.y, v1.z, v1.w};
#pragma unroll
        for (int q = 0; q < 4; ++q) {
            vals[q * 2]     = b2f((u16)(w0[q] & 0xffffu));
            vals[q * 2 + 1] = b2f((u16)(w0[q] >> 16));
            vals[8 + q * 2]     = b2f((u16)(w1[q] & 0xffffu));
            vals[8 + q * 2 + 1] = b2f((u16)(w1[q] >> 16));
        }
    }
    float s = 0.f, ss = 0.f;
#pragma unroll
    for (int i = 0; i < 16; ++i) { s += vals[i]; ss += vals[i] * vals[i]; }

    float4 gv[4], bv[4];
    gv[0] = *(const float4*)&g[t * 8];
    gv[1] = *(const float4*)&g[t * 8 + 4];
    gv[2] = *(const float4*)&g[(t + 256) * 8];
    gv[3] = *(const float4*)&g[(t + 256) * 8 + 4];
    bv[0] = *(const float4*)&be[t * 8];
    bv[1] = *(const float4*)&be[t * 8 + 4];
    bv[2] = *(const float4*)&be[(t + 256) * 8];
    bv[3] = *(const float4*)&be[(t + 256) * 8 + 4];

#pragma unroll
    for (int off = 32; off > 0; off >>= 1) {
        s += __shfl_down(s, off, 64);
        ss += __shfl_down(ss, off, 64);
    }
    if ((t & 63) == 0) { red[(t >> 6) * 2] = s; red[(t >> 6) * 2 + 1] = ss; }
    __syncthreads();
    s  = red[0] + red[2] + red[4] + red[6];
    ss = red[1] + red[3] + red[5] + red[7];
    const float mean = s * (1.f / HID_DIM);
    const float rstd = rsqrtf(ss * (1.f / HID_DIM) - mean * mean + 1e-5f);

    const float* gf = (const float*)gv;
    const float* bf = (const float*)bv;
#pragma unroll
    for (int j = 0; j < 2; ++j) {
        uint4 o;
        uint32_t* ow = (uint32_t*)&o;
#pragma unroll
        for (int q = 0; q < 4; ++q) {
            const int k = j * 8 + q * 2;
            float u0 = gelu_fast((vals[k]     - mean) * rstd * gf[k]     + bf[k]);
            float u1 = gelu_fast((vals[k + 1] - mean) * rstd * gf[k + 1] + bf[k + 1]);
            ow[q] = (uint32_t)f2b(u0) | ((uint32_t)f2b(u1) << 16);
        }
        *(uint4*)&hp[(t + j * 256) * 8] = o;
    }
}

// ---------- fused LN(1024) + GELU + weighted accumulate (bf16 y path) ----------
__global__ __launch_bounds__(256)
void ln_gelu_combine(const u16* __restrict__ y, const float* __restrict__ g,
                     const float* __restrict__ be, const float* __restrict__ wts,
                     float* __restrict__ out, int e, int first) {
    __shared__ float red[8];
    const int row = blockIdx.x;
    const u16* yp = y + (size_t)row * OUT_DIM;
    const int t = threadIdx.x;

    uint2 v = *(const uint2*)&yp[t * 4];
    float f0 = b2f((u16)(v.x & 0xffffu)), f1 = b2f((u16)(v.x >> 16));
    float f2 = b2f((u16)(v.y & 0xffffu)), f3 = b2f((u16)(v.y >> 16));
    float s = f0 + f1 + f2 + f3;
    float ss = f0 * f0 + f1 * f1 + f2 * f2 + f3 * f3;

    const int n = t * 4;
    float4 gv = *(const float4*)&g[n];
    float4 bvv = *(const float4*)&be[n];

#pragma unroll
    for (int off = 32; off > 0; off >>= 1) {
        s += __shfl_down(s, off, 64);
        ss += __shfl_down(ss, off, 64);
    }
    if ((t & 63) == 0) { red[(t >> 6) * 2] = s; red[(t >> 6) * 2 + 1] = ss; }
    __syncthreads();
    s  = red[0] + red[2] + red[4] + red[6];
    ss = red[1] + red[3] + red[5] + red[7];
    const float mean = s * (1.f / OUT_DIM);
    const float rstd = rsqrtf(ss * (1.f / OUT_DIM) - mean * mean + 1e-5f);

    const float w = wts[(size_t)row * NEXP + e];
    float4 o;
    if (first) { o.x = o.y = o.z = o.w = 0.f; }
    else       { o = *(const float4*)&out[(size_t)row * OUT_DIM + n]; }
    o.x += w * gelu_fast((f0 - mean) * rstd * gv.x + bvv.x);
    o.y += w * gelu_fast((f1 - mean) * rstd * gv.y + bvv.y);
    o.z += w * gelu_fast((f2 - mean) * rstd * gv.z + bvv.z);
    o.w += w * gelu_fast((f3 - mean) * rstd * gv.w + bvv.w);
    *(float4*)&out[(size_t)row * OUT_DIM + n] = o;
}

// ---------- split-K combine: y = p0+p1+b2 (bf16 partials), LN+GELU+acc ----------
__global__ __launch_bounds__(256)
void ln_gelu_combine_2bf(const u16* __restrict__ P, const float* __restrict__ g,
                         const float* __restrict__ be, const float* __restrict__ bs,
                         const float* __restrict__ wts, float* __restrict__ out,
                         int e, int first) {
    __shared__ float red[8];
    const int row = blockIdx.x;
    const int t = threadIdx.x;
    const int n = t * 4;

    const u16* p0 = P + (size_t)row * OUT_DIM + n;
    const u16* p1 = p0 + (size_t)B_DIM * OUT_DIM;
    uint2 a = *(const uint2*)p0;
    uint2 b = *(const uint2*)p1;
    float4 c  = *(const float4*)&bs[n];
    float f0 = b2f((u16)(a.x & 0xffffu)) + b2f((u16)(b.x & 0xffffu)) + c.x;
    float f1 = b2f((u16)(a.x >> 16))     + b2f((u16)(b.x >> 16))     + c.y;
    float f2 = b2f((u16)(a.y & 0xffffu)) + b2f((u16)(b.y & 0xffffu)) + c.z;
    float f3 = b2f((u16)(a.y >> 16))     + b2f((u16)(b.y >> 16))     + c.w;
    float s = f0 + f1 + f2 + f3;
    float ss = f0 * f0 + f1 * f1 + f2 * f2 + f3 * f3;

    float4 gv = *(const float4*)&g[n];
    float4 bvv = *(const float4*)&be[n];

#pragma unroll
    for (int off = 32; off > 0; off >>= 1) {
        s += __shfl_down(s, off, 64);
        ss += __shfl_down(ss, off, 64);
    }
    if ((t & 63) == 0) { red[(t >> 6) * 2] = s; red[(t >> 6) * 2 + 1] = ss; }
    __syncthreads();
    s  = red[0] + red[2] + red[4] + red[6];
    ss = red[1] + red[3] + red[5] + red[7];
    const float mean = s * (1.f / OUT_DIM);
    const float rstd = rsqrtf(ss * (1.f / OUT_DIM) - mean * mean + 1e-5f);

    const float w = wts[(size_t)row * NEXP + e];
    float4 o;
    if (first) { o.x = o.y = o.z = o.w = 0.f; }
    else       { o = *(const float4*)&out[(size_t)row * OUT_DIM + n]; }
    o.x += w * gelu_fast((f0 - mean) * rstd * gv.x + bvv.x);
    o.y += w * gelu_fast((f1 - mean) * rstd * gv.y + bvv.y);
    o.z += w * gelu_fast((f2 - mean) * rstd * gv.z + bvv.z);
    o.w += w * gelu_fast((f3 - mean) * rstd * gv.w + bvv.w);
    *(float4*)&out[(size_t)row * OUT_DIM + n] = o;
}

// ---------- launch ----------
extern "C" void kernel_launch(void* const* d_in, const int* in_sizes, int n_in,
                              void* d_out, int out_size, void* d_ws, size_t ws_size,
                              hipStream_t stream) {
    (void)in_sizes; (void)n_in; (void)out_size;
    const float* x   = (const float*)d_in[0];  // [8192,1024]
    const float* wts = (const float*)d_in[1];  // [8192,8]
    const float* W1  = (const float*)d_in[2];  // [8,1024,4096]
    const float* b1  = (const float*)d_in[3];  // [8,4096]
    const float* g1  = (const float*)d_in[4];  // [8,4096]
    const float* be1 = (const float*)d_in[5];  // [8,4096]
    const float* W2  = (const float*)d_in[6];  // [8,4096,1024]
    const float* b2  = (const float*)d_in[7];  // [8,1024]
    const float* g2  = (const float*)d_in[8];  // [8,1024]
    const float* be2 = (const float*)d_in[9];  // [8,1024]
    float* out = (float*)d_out;                // [8192,1024]

    // workspace carve: xb 16MB | w1t 8MB | w2t 8MB | h 64MB | P 32MB (bf16 x2)
    char* p = (char*)d_ws;
    u16* xb  = (u16*)p; p += (size_t)B_DIM * IN_DIM * 2;
    u16* w1t = (u16*)p; p += (size_t)HID_DIM * IN_DIM * 2;
    u16* w2t = (u16*)p; p += (size_t)OUT_DIM * HID_DIM * 2;
    u16* h   = (u16*)p; p += (size_t)B_DIM * HID_DIM * 2;
    u16* P   = (u16*)p;                        // split path: 2 x 16MB bf16 partials
    u16* y   = (u16*)p;                        // fallback path: 16MB bf16

    const size_t need = (size_t)B_DIM * IN_DIM * 2 + (size_t)HID_DIM * IN_DIM * 2 +
                        (size_t)OUT_DIM * HID_DIM * 2 + (size_t)B_DIM * HID_DIM * 2 +
                        (size_t)2 * B_DIM * OUT_DIM * 2;   // 128 MB
    const int splitk = (ws_size >= need) ? 1 : 0;

    cvt_bf16<<<(B_DIM * IN_DIM / 4 + 255) / 256, 256, 0, stream>>>(x, xb, B_DIM * IN_DIM / 4);

    for (int e = 0; e < NEXP; ++e) {
        transpose_cvt2<<<dim3(HID_DIM / 32, IN_DIM / 32, 2), 256, 0, stream>>>(
            W1 + (size_t)e * IN_DIM * HID_DIM, w1t,
            W2 + (size_t)e * HID_DIM * OUT_DIM, w2t);
        // h = xb @ W1[e] + b1[e]   (M=8192, N=4096, K=1024) — R3-verified 8-phase
        gemm256_8ph<0><<<dim3(HID_DIM / 256, B_DIM / 256, 1), 512, 0, stream>>>(
            xb, w1t, b1 + (size_t)e * HID_DIM, h, B_DIM, HID_DIM, IN_DIM, IN_DIM, IN_DIM);
        // h = gelu(ln(h))
        ln_gelu_hid<<<B_DIM, 256, 0, stream>>>(h, g1 + (size_t)e * HID_DIM,
                                               be1 + (size_t)e * HID_DIM);
        if (splitk) {
            // P[s] = h @ W2[e] (K-slice s of 2048), bf16 partials; 256 blocks
            gemm256_8ph<1><<<dim3(OUT_DIM / 256, B_DIM / 256, 2), 512, 0, stream>>>(
                h, w2t, nullptr, P, B_DIM, OUT_DIM, HID_DIM, HID_DIM, HID_DIM / 2);
            // out (+)= wts[:,e] * gelu(ln(p0+p1+b2))
            ln_gelu_combine_2bf<<<B_DIM, 256, 0, stream>>>(
                P, g2 + (size_t)e * OUT_DIM, be2 + (size_t)e * OUT_DIM,
                b2 + (size_t)e * OUT_DIM, wts, out, e, e == 0 ? 1 : 0);
        } else {
            // fallback: 128^2 GEMM2 + bf16 combine
            gemm_bt_bias<<<dim3(OUT_DIM / 128, B_DIM / 128), 256, 0, stream>>>(
                h, w2t, b2 + (size_t)e * OUT_DIM, y, B_DIM, OUT_DIM, HID_DIM);
            ln_gelu_combine<<<B_DIM, 256, 0, stream>>>(y, g2 + (size_t)e * OUT_DIM,
                                                       be2 + (size_t)e * OUT_DIM, wts, out,
                                                       e, e == 0 ? 1 : 0);
        }
    }
}

// Round 7
// 1864.233 us; speedup vs baseline: 2.9670x; 1.0100x over previous
//
#include <hip/hip_runtime.h>
#include <cstdint>
#include <cstddef>

typedef unsigned short u16;
typedef float f32x4 __attribute__((ext_vector_type(4)));
typedef __bf16 bf16x8 __attribute__((ext_vector_type(8)));

#define B_DIM   8192
#define IN_DIM  1024
#define HID_DIM 4096
#define OUT_DIM 1024
#define NEXP    8

// ---------- helpers ----------
__device__ __forceinline__ u16 f2b(float f) {
    uint32_t u = __builtin_bit_cast(uint32_t, f);
    u += 0x7fffu + ((u >> 16) & 1u);      // RNE
    return (u16)(u >> 16);
}
__device__ __forceinline__ float b2f(u16 b) {
    uint32_t u = ((uint32_t)b) << 16;
    return __builtin_bit_cast(float, u);
}
// tanh-form GELU via one v_exp_f32: gelu(x) = x * e/(e+1), e = exp(2*y).
__device__ __forceinline__ float gelu_fast(float x) {
    float y = x * (0.7978845608f + 0.03567740814f * x * x);
    float a = fminf(y * 2.8853900818f, 80.0f);     // 2*log2(e)*y, clamp overflow
    float e = __builtin_amdgcn_exp2f(a);
    return x * e * __builtin_amdgcn_rcpf(e + 1.0f);
}
__device__ __forceinline__ void async_cp16(const void* g, void* l) {
    __builtin_amdgcn_global_load_lds(
        (const __attribute__((address_space(1))) void*)g,
        (__attribute__((address_space(3))) void*)l,
        16, 0, 0);
}

// ---------- fp32 -> bf16 convert ----------
__global__ __launch_bounds__(256)
void cvt_bf16(const float* __restrict__ in, u16* __restrict__ out, int n4) {
    int i = blockIdx.x * 256 + threadIdx.x;
    if (i >= n4) return;
    float4 v = *(const float4*)&in[(size_t)i * 4];
    uint2 o;
    o.x = (uint32_t)f2b(v.x) | ((uint32_t)f2b(v.y) << 16);
    o.y = (uint32_t)f2b(v.z) | ((uint32_t)f2b(v.w) << 16);
    *(uint2*)&out[(size_t)i * 4] = o;
}

// ---------- transpose both expert weights: [K,N] fp32 -> [N,K] bf16 ----------
__global__ __launch_bounds__(256)
void transpose_cvt2(const float* __restrict__ W1e, u16* __restrict__ w1t,
                    const float* __restrict__ W2e, u16* __restrict__ w2t) {
    __shared__ float tile[32][33];
    const float* W; u16* Wt; int K, N, n0, k0;
    if (blockIdx.z == 0) {
        W = W1e; Wt = w1t; K = IN_DIM; N = HID_DIM;
        n0 = blockIdx.x * 32; k0 = blockIdx.y * 32;
    } else {
        W = W2e; Wt = w2t; K = HID_DIM; N = OUT_DIM;
        n0 = blockIdx.y * 32; k0 = blockIdx.x * 32;
    }
    const int tx = threadIdx.x & 31, ty = threadIdx.x >> 5;   // ty 0..7
#pragma unroll
    for (int i = 0; i < 4; ++i) {
        int k = k0 + ty + i * 8;
        tile[ty + i * 8][tx] = W[(size_t)k * N + n0 + tx];
    }
    __syncthreads();
#pragma unroll
    for (int i = 0; i < 4; ++i) {
        int n = n0 + ty + i * 8;
        Wt[(size_t)n * K + k0 + tx] = f2b(tile[tx][ty + i * 8]);
    }
}

// ---------- 256x256 bf16 GEMM, 8-phase schedule (R3/R6-verified structure) ----------
// C = A[M,K(lda)] * Bt[N,K(ldb)]^T. PARTIAL=0: +bias, bf16 out.
// PARTIAL=1: bf16 partial out at z*M*N (split-K via blockIdx.z, depth Ksl).
// 512 thr = 8 waves (2M x 4N), per-wave 128x64 (acc[8][4] = 128 acc regs;
// R5 lesson: this acc footprint + 512 threads is the register-file ceiling).
// BK=64 staged as two k-halves of 256x32. 4 phases/K-tile, counted vmcnt(4)
// at ph1/ph3. 2-buffer LDS (128 KiB, 1 block/CU). Swizzle verified 0-conflict.
// Requires NT=Ksl/64 >= 2, N%256==0, M%256==0, gridDim.y % 8 == 0.
template<int PARTIAL>
__global__ __launch_bounds__(512, 2)
void gemm256_8ph(const u16* __restrict__ A, const u16* __restrict__ Bt,
                 const float* __restrict__ bias, u16* __restrict__ C,
                 int M, int N, int lda, int ldb, int Ksl) {
    __shared__ __attribute__((aligned(16))) u16 sA[32768];  // [2 buf][2 kh][256*32]
    __shared__ __attribute__((aligned(16))) u16 sB[32768];

    const int tid  = threadIdx.x;
    const int wid  = tid >> 6;
    const int lane = tid & 63;
    const int quad = lane >> 4;
    const int lr   = lane & 15;
    const int wm   = wid >> 2;        // 0..1
    const int wn   = wid & 3;         // 0..3
    const int z    = blockIdx.z;      // K-slice (split-K); 0 otherwise

    // XCD-aware supertile swizzle (NY multiple of 8).
    const int NX = gridDim.x, NY = gridDim.y;
    const int bid = blockIdx.y * NX + blockIdx.x;
    const int xcd = bid & 7;
    const int j   = bid >> 3;
    const int yl  = j / NX;
    const int bx  = j - yl * NX;
    const int by  = xcd * (NY >> 3) + yl;
    const int m0 = by * 256;
    const int n0 = bx * 256;

    const int qsw   = (lr >> 1) & 3;                       // read-side XOR
    const int row_s = tid >> 2;                            // 0..127 staging row
    const int lc    = ((tid & 3) ^ ((tid >> 3) & 3)) * 8;  // pre-swizzled src chunk

    const u16* Ast = A  + (size_t)z * Ksl + (size_t)(m0 + row_s) * lda + lc;
    const u16* Bst = Bt + (size_t)z * Ksl + (size_t)(n0 + row_s) * ldb + lc;

    const int rdA = (wm * 128 + lr) * 32 + ((quad ^ qsw) * 8);
    const int rdB = (wn * 64  + lr) * 32 + ((quad ^ qsw) * 8);
    const int d0  = tid * 8;          // staging dest within a k-half

    const int NT = Ksl >> 6;          // BK=64 tiles (>= 2)

    f32x4 acc[8][4] = {};
    bf16x8 av[4], bv[4];

#define STG_A(hb, ko) do {                                                     \
        async_cp16(Ast + (ko),                      &sA[(hb) + d0]);           \
        async_cp16(Ast + (ko) + (size_t)128 * lda,  &sA[(hb) + d0 + 4096]);    \
    } while (0)
#define STG_B(hb, ko) do {                                                     \
        async_cp16(Bst + (ko),                      &sB[(hb) + d0]);           \
        async_cp16(Bst + (ko) + (size_t)128 * ldb,  &sB[(hb) + d0 + 4096]);    \
    } while (0)
#define RD_A4(hb, MO) do { _Pragma("unroll")                                   \
        for (int mi_ = 0; mi_ < 4; ++mi_)                                      \
            av[mi_] = *(const bf16x8*)&sA[(hb) + rdA + ((MO) + mi_) * 512];    \
    } while (0)
#define RD_B4(hb) do { _Pragma("unroll")                                       \
        for (int ni_ = 0; ni_ < 4; ++ni_)                                      \
            bv[ni_] = *(const bf16x8*)&sB[(hb) + rdB + ni_ * 512];             \
    } while (0)
#define SYNC_MFMA16(MO) do {                                                   \
        __builtin_amdgcn_s_barrier();                                          \
        asm volatile("s_waitcnt lgkmcnt(0)");                                  \
        __builtin_amdgcn_sched_barrier(0);                                     \
        __builtin_amdgcn_s_setprio(1);                                         \
        _Pragma("unroll")                                                      \
        for (int mi_ = 0; mi_ < 4; ++mi_)                                      \
            _Pragma("unroll")                                                  \
            for (int ni_ = 0; ni_ < 4; ++ni_)                                  \
                acc[(MO) + mi_][ni_] = __builtin_amdgcn_mfma_f32_16x16x32_bf16(\
                    av[mi_], bv[ni_], acc[(MO) + mi_][ni_], 0, 0, 0);          \
        __builtin_amdgcn_s_setprio(0);                                         \
    } while (0)

    // prologue: stage tile 0 fully (Ak0,Bk0,Ak1,Bk1); publish k-half 0
    STG_A(0, 0);      STG_B(0, 0);
    STG_A(8192, 32);  STG_B(8192, 32);
    asm volatile("s_waitcnt vmcnt(4)");
    __builtin_amdgcn_s_barrier();

#pragma unroll 1
    for (int t = 0; t < NT - 1; ++t) {
        const int cb = (t & 1) << 14;          // current buf base (0 / 16384)
        const int nb = cb ^ 16384;             // next buf base
        const size_t kt = (size_t)(t + 1) * 64;
        // ph0: kh0, mi 0-3 (+all B kh0); stage Ak0(t+1)
        RD_A4(cb, 0); RD_B4(cb);
        STG_A(nb, kt);
        SYNC_MFMA16(0);
        __builtin_amdgcn_s_barrier();
        // ph1: kh0, mi 4-7 (B reused); stage Bk0(t+1); publish kh1(t)
        RD_A4(cb, 4);
        STG_B(nb, kt);
        SYNC_MFMA16(4);
        asm volatile("s_waitcnt vmcnt(4)");
        __builtin_amdgcn_s_barrier();
        // ph2: kh1, mi 0-3 (+all B kh1); stage Ak1(t+1)
        RD_A4(cb + 8192, 0); RD_B4(cb + 8192);
        STG_A(nb + 8192, kt + 32);
        SYNC_MFMA16(0);
        __builtin_amdgcn_s_barrier();
        // ph3: kh1, mi 4-7; stage Bk1(t+1); publish kh0(t+1)
        RD_A4(cb + 8192, 4);
        STG_B(nb + 8192, kt + 32);
        SYNC_MFMA16(4);
        asm volatile("s_waitcnt vmcnt(4)");
        __builtin_amdgcn_s_barrier();
    }
    {   // peeled last tile: no staging, exact drains
        const int cb = ((NT - 1) & 1) << 14;
        RD_A4(cb, 0); RD_B4(cb);
        SYNC_MFMA16(0);
        __builtin_amdgcn_s_barrier();
        RD_A4(cb, 4);
        SYNC_MFMA16(4);
        asm volatile("s_waitcnt vmcnt(0)");    // publish kh1 of last tile
        __builtin_amdgcn_s_barrier();
        RD_A4(cb + 8192, 0); RD_B4(cb + 8192);
        SYNC_MFMA16(0);
        __builtin_amdgcn_s_barrier();
        RD_A4(cb + 8192, 4);
        SYNC_MFMA16(4);
    }
#undef SYNC_MFMA16
#undef RD_B4
#undef RD_A4
#undef STG_B
#undef STG_A

    // epilogue: D col = lane&15, row = quad*4 + reg
    if constexpr (PARTIAL) {
        u16* Pb = C + (size_t)z * ((size_t)M * N);
#pragma unroll
        for (int mi = 0; mi < 8; ++mi) {
            const int mr = m0 + wm * 128 + mi * 16 + quad * 4;
#pragma unroll
            for (int r = 0; r < 4; ++r) {
                u16* Prow = Pb + (size_t)(mr + r) * N + n0 + wn * 64 + lr;
#pragma unroll
                for (int ni = 0; ni < 4; ++ni)
                    Prow[ni * 16] = f2b(acc[mi][ni][r]);
            }
        }
    } else {
        float bvv[4];
#pragma unroll
        for (int ni = 0; ni < 4; ++ni)
            bvv[ni] = bias[n0 + wn * 64 + ni * 16 + lr];
#pragma unroll
        for (int mi = 0; mi < 8; ++mi) {
            const int mr = m0 + wm * 128 + mi * 16 + quad * 4;
#pragma unroll
            for (int r = 0; r < 4; ++r) {
                u16* Crow = C + (size_t)(mr + r) * N + n0 + wn * 64 + lr;
#pragma unroll
                for (int ni = 0; ni < 4; ++ni)
                    Crow[ni * 16] = f2b(acc[mi][ni][r] + bvv[ni]);
            }
        }
    }
}

// ---------- bf16 GEMM 128x128 (fallback for GEMM2 if ws too small) ----------
__global__ __launch_bounds__(256)
void gemm_bt_bias(const u16* __restrict__ A, const u16* __restrict__ Bt,
                  const float* __restrict__ bias, u16* __restrict__ C,
                  int M, int N, int K) {
    __shared__ __attribute__((aligned(16))) u16 sA[2][128 * 32];
    __shared__ __attribute__((aligned(16))) u16 sB[2][128 * 32];

    const int tid  = threadIdx.x;
    const int wid  = tid >> 6;
    const int lane = tid & 63;
    const int quad = lane >> 4;
    const int lr   = lane & 15;
    const int wm   = wid & 1;
    const int wn   = wid >> 1;

    const int NX = gridDim.x, NY = gridDim.y;
    const int bid = blockIdx.y * NX + blockIdx.x;
    const int xcd = bid & 7;
    const int j   = bid >> 3;
    const int yl  = j / NX;
    const int bx  = j - yl * NX;
    const int by  = xcd * (NY >> 3) + yl;

    const int m0 = by * 128;
    const int n0 = bx * 128;

    const int sr  = lane >> 2;
    const int scl = ((lane & 3) ^ ((lane >> 3) & 3)) * 8;
    const int qsw = (lr >> 1) & 3;

    const u16* Ag = A + (size_t)m0 * K;
    const u16* Bg = Bt + (size_t)n0 * K;

    f32x4 acc[4][4] = {};

    for (int k0 = 0; k0 < K; k0 += 64) {
#pragma unroll
        for (int s = 0; s < 2; ++s) {
#pragma unroll
            for (int i = 0; i < 2; ++i) {
                const int rb = wid * 32 + i * 16;
                async_cp16(Ag + (size_t)(rb + sr) * K + k0 + s * 32 + scl,
                           &sA[s][rb * 32]);
                async_cp16(Bg + (size_t)(rb + sr) * K + k0 + s * 32 + scl,
                           &sB[s][rb * 32]);
            }
        }
        __syncthreads();

#pragma unroll
        for (int s = 0; s < 2; ++s) {
            bf16x8 af[4], bfr[4];
#pragma unroll
            for (int mi = 0; mi < 4; ++mi)
                af[mi] = *(const bf16x8*)
                    &sA[s][(wm * 64 + mi * 16 + lr) * 32 + ((quad ^ qsw) * 8)];
#pragma unroll
            for (int ni = 0; ni < 4; ++ni)
                bfr[ni] = *(const bf16x8*)
                    &sB[s][(wn * 64 + ni * 16 + lr) * 32 + ((quad ^ qsw) * 8)];

#pragma unroll
            for (int mi = 0; mi < 4; ++mi)
#pragma unroll
                for (int ni = 0; ni < 4; ++ni)
                    acc[mi][ni] = __builtin_amdgcn_mfma_f32_16x16x32_bf16(
                        af[mi], bfr[ni], acc[mi][ni], 0, 0, 0);
        }

        __syncthreads();
    }

    float bvv[4];
#pragma unroll
    for (int ni = 0; ni < 4; ++ni)
        bvv[ni] = bias[n0 + wn * 64 + ni * 16 + lr];

#pragma unroll
    for (int mi = 0; mi < 4; ++mi) {
        const int mr = m0 + wm * 64 + mi * 16 + quad * 4;
#pragma unroll
        for (int r = 0; r < 4; ++r) {
            u16* Crow = C + (size_t)(mr + r) * N + n0 + wn * 64 + lr;
#pragma unroll
            for (int ni = 0; ni < 4; ++ni)
                Crow[ni * 16] = f2b(acc[mi][ni][r] + bvv[ni]);
        }
    }
}

// ---------- fused LN(4096) + GELU, in-place on bf16 h ----------
__global__ __launch_bounds__(256)
void ln_gelu_hid(u16* __restrict__ h, const float* __restrict__ g,
                 const float* __restrict__ be) {
    __shared__ float red[8];
    const int row = blockIdx.x;
    u16* hp = h + (size_t)row * HID_DIM;
    const int t = threadIdx.x;

    uint4 v0 = *(const uint4*)&hp[t * 8];
    uint4 v1 = *(const uint4*)&hp[(t + 256) * 8];

    float vals[16];
    {
        const uint32_t w0[4] = {v0.x, v0.y, v0.z, v0.w};
        const uint32_t w1[4] = {v1.x, v1.y, v1.z, v1.w};
#pragma unroll
        for (int q = 0; q < 4; ++q) {
            vals[q * 2]     = b2f((u16)(w0[q] & 0xffffu));
            vals[q * 2 + 1] = b2f((u16)(w0[q] >> 16));
            vals[8 + q * 2]     = b2f((u16)(w1[q] & 0xffffu));
            vals[8 + q * 2 + 1] = b2f((u16)(w1[q] >> 16));
        }
    }
    float s = 0.f, ss = 0.f;
#pragma unroll
    for (int i = 0; i < 16; ++i) { s += vals[i]; ss += vals[i] * vals[i]; }

    float4 gv[4], bv[4];
    gv[0] = *(const float4*)&g[t * 8];
    gv[1] = *(const float4*)&g[t * 8 + 4];
    gv[2] = *(const float4*)&g[(t + 256) * 8];
    gv[3] = *(const float4*)&g[(t + 256) * 8 + 4];
    bv[0] = *(const float4*)&be[t * 8];
    bv[1] = *(const float4*)&be[t * 8 + 4];
    bv[2] = *(const float4*)&be[(t + 256) * 8];
    bv[3] = *(const float4*)&be[(t + 256) * 8 + 4];

#pragma unroll
    for (int off = 32; off > 0; off >>= 1) {
        s += __shfl_down(s, off, 64);
        ss += __shfl_down(ss, off, 64);
    }
    if ((t & 63) == 0) { red[(t >> 6) * 2] = s; red[(t >> 6) * 2 + 1] = ss; }
    __syncthreads();
    s  = red[0] + red[2] + red[4] + red[6];
    ss = red[1] + red[3] + red[5] + red[7];
    const float mean = s * (1.f / HID_DIM);
    const float rstd = rsqrtf(ss * (1.f / HID_DIM) - mean * mean + 1e-5f);

    const float* gf = (const float*)gv;
    const float* bf = (const float*)bv;
#pragma unroll
    for (int j = 0; j < 2; ++j) {
        uint4 o;
        uint32_t* ow = (uint32_t*)&o;
#pragma unroll
        for (int q = 0; q < 4; ++q) {
            const int k = j * 8 + q * 2;
            float u0 = gelu_fast((vals[k]     - mean) * rstd * gf[k]     + bf[k]);
            float u1 = gelu_fast((vals[k + 1] - mean) * rstd * gf[k + 1] + bf[k + 1]);
            ow[q] = (uint32_t)f2b(u0) | ((uint32_t)f2b(u1) << 16);
        }
        *(uint4*)&hp[(t + j * 256) * 8] = o;
    }
}

// ---------- fused LN(1024) + GELU + weighted accumulate (bf16 y path) ----------
__global__ __launch_bounds__(256)
void ln_gelu_combine(const u16* __restrict__ y, const float* __restrict__ g,
                     const float* __restrict__ be, const float* __restrict__ wts,
                     float* __restrict__ out, int e, int first) {
    __shared__ float red[8];
    const int row = blockIdx.x;
    const u16* yp = y + (size_t)row * OUT_DIM;
    const int t = threadIdx.x;

    uint2 v = *(const uint2*)&yp[t * 4];
    float f0 = b2f((u16)(v.x & 0xffffu)), f1 = b2f((u16)(v.x >> 16));
    float f2 = b2f((u16)(v.y & 0xffffu)), f3 = b2f((u16)(v.y >> 16));
    float s = f0 + f1 + f2 + f3;
    float ss = f0 * f0 + f1 * f1 + f2 * f2 + f3 * f3;

    const int n = t * 4;
    float4 gv = *(const float4*)&g[n];
    float4 bvv = *(const float4*)&be[n];

#pragma unroll
    for (int off = 32; off > 0; off >>= 1) {
        s += __shfl_down(s, off, 64);
        ss += __shfl_down(ss, off, 64);
    }
    if ((t & 63) == 0) { red[(t >> 6) * 2] = s; red[(t >> 6) * 2 + 1] = ss; }
    __syncthreads();
    s  = red[0] + red[2] + red[4] + red[6];
    ss = red[1] + red[3] + red[5] + red[7];
    const float mean = s * (1.f / OUT_DIM);
    const float rstd = rsqrtf(ss * (1.f / OUT_DIM) - mean * mean + 1e-5f);

    const float w = wts[(size_t)row * NEXP + e];
    float4 o;
    if (first) { o.x = o.y = o.z = o.w = 0.f; }
    else       { o = *(const float4*)&out[(size_t)row * OUT_DIM + n]; }
    o.x += w * gelu_fast((f0 - mean) * rstd * gv.x + bvv.x);
    o.y += w * gelu_fast((f1 - mean) * rstd * gv.y + bvv.y);
    o.z += w * gelu_fast((f2 - mean) * rstd * gv.z + bvv.z);
    o.w += w * gelu_fast((f3 - mean) * rstd * gv.w + bvv.w);
    *(float4*)&out[(size_t)row * OUT_DIM + n] = o;
}

// ---------- grouped split-K combine: for i<G experts, y_i = P[i,0]+P[i,1]+b2[e0+i],
// LN+GELU per expert, out (+)= sum_i w_i * u_i. ONE out round-trip per group.
// G uniform across grid (1,2,4); all f/mean/rstd arrays static-indexed (rule #20).
__global__ __launch_bounds__(256)
void ln_gelu_combine_g(const u16* __restrict__ P, const float* __restrict__ g2,
                       const float* __restrict__ be2, const float* __restrict__ b2,
                       const float* __restrict__ wts, float* __restrict__ out,
                       int e0, int G, int first) {
    __shared__ float red[32];
    const int row = blockIdx.x;
    const int t = threadIdx.x;
    const int n = t * 4;

    float f[4][4];
    float sv[8];
#pragma unroll
    for (int i = 0; i < 4; ++i) {
        if (i < G) {
            const u16* p0 = P + (size_t)i * 2 * B_DIM * OUT_DIM
                              + (size_t)row * OUT_DIM + n;
            const u16* p1 = p0 + (size_t)B_DIM * OUT_DIM;
            uint2 a = *(const uint2*)p0;
            uint2 b = *(const uint2*)p1;
            float4 c = *(const float4*)&b2[(size_t)(e0 + i) * OUT_DIM + n];
            f[i][0] = b2f((u16)(a.x & 0xffffu)) + b2f((u16)(b.x & 0xffffu)) + c.x;
            f[i][1] = b2f((u16)(a.x >> 16))     + b2f((u16)(b.x >> 16))     + c.y;
            f[i][2] = b2f((u16)(a.y & 0xffffu)) + b2f((u16)(b.y & 0xffffu)) + c.z;
            f[i][3] = b2f((u16)(a.y >> 16))     + b2f((u16)(b.y >> 16))     + c.w;
            sv[i * 2]     = f[i][0] + f[i][1] + f[i][2] + f[i][3];
            sv[i * 2 + 1] = f[i][0] * f[i][0] + f[i][1] * f[i][1]
                          + f[i][2] * f[i][2] + f[i][3] * f[i][3];
        } else { sv[i * 2] = 0.f; sv[i * 2 + 1] = 0.f; }
    }

#pragma unroll
    for (int off = 32; off > 0; off >>= 1)
#pragma unroll
        for (int i = 0; i < 8; ++i)
            if (i < (G << 1)) sv[i] += __shfl_down(sv[i], off, 64);
    if ((t & 63) == 0) {
#pragma unroll
        for (int i = 0; i < 8; ++i) red[(t >> 6) * 8 + i] = sv[i];
    }
    __syncthreads();
#pragma unroll
    for (int i = 0; i < 8; ++i)
        sv[i] = red[i] + red[8 + i] + red[16 + i] + red[24 + i];

    float mean[4], rstd[4];
#pragma unroll
    for (int i = 0; i < 4; ++i) {
        mean[i] = sv[i * 2] * (1.f / OUT_DIM);
        rstd[i] = rsqrtf(sv[i * 2 + 1] * (1.f / OUT_DIM) - mean[i] * mean[i] + 1e-5f);
    }

    float4 o;
    if (first) { o.x = o.y = o.z = o.w = 0.f; }
    else       { o = *(const float4*)&out[(size_t)row * OUT_DIM + n]; }
#pragma unroll
    for (int i = 0; i < 4; ++i) {
        if (i < G) {
            const float w = wts[(size_t)row * NEXP + e0 + i];
            float4 gv  = *(const float4*)&g2[(size_t)(e0 + i) * OUT_DIM + n];
            float4 bvv = *(const float4*)&be2[(size_t)(e0 + i) * OUT_DIM + n];
            o.x += w * gelu_fast((f[i][0] - mean[i]) * rstd[i] * gv.x + bvv.x);
            o.y += w * gelu_fast((f[i][1] - mean[i]) * rstd[i] * gv.y + bvv.y);
            o.z += w * gelu_fast((f[i][2] - mean[i]) * rstd[i] * gv.z + bvv.z);
            o.w += w * gelu_fast((f[i][3] - mean[i]) * rstd[i] * gv.w + bvv.w);
        }
    }
    *(float4*)&out[(size_t)row * OUT_DIM + n] = o;
}

// ---------- launch ----------
extern "C" void kernel_launch(void* const* d_in, const int* in_sizes, int n_in,
                              void* d_out, int out_size, void* d_ws, size_t ws_size,
                              hipStream_t stream) {
    (void)in_sizes; (void)n_in; (void)out_size;
    const float* x   = (const float*)d_in[0];  // [8192,1024]
    const float* wts = (const float*)d_in[1];  // [8192,8]
    const float* W1  = (const float*)d_in[2];  // [8,1024,4096]
    const float* b1  = (const float*)d_in[3];  // [8,4096]
    const float* g1  = (const float*)d_in[4];  // [8,4096]
    const float* be1 = (const float*)d_in[5];  // [8,4096]
    const float* W2  = (const float*)d_in[6];  // [8,4096,1024]
    const float* b2  = (const float*)d_in[7];  // [8,1024]
    const float* g2  = (const float*)d_in[8];  // [8,1024]
    const float* be2 = (const float*)d_in[9];  // [8,1024]
    float* out = (float*)d_out;                // [8192,1024]

    // workspace carve: xb 16MB | w1t 8MB | w2t 8MB | h 64MB | P G*32MB (bf16, 2 slices/expert)
    char* p = (char*)d_ws;
    u16* xb  = (u16*)p; p += (size_t)B_DIM * IN_DIM * 2;
    u16* w1t = (u16*)p; p += (size_t)HID_DIM * IN_DIM * 2;
    u16* w2t = (u16*)p; p += (size_t)OUT_DIM * HID_DIM * 2;
    u16* h   = (u16*)p; p += (size_t)B_DIM * HID_DIM * 2;
    u16* P   = (u16*)p;                        // split path: G x 2 x 16MB bf16 partials
    u16* y   = (u16*)p;                        // fallback path: 16MB bf16

    const size_t base = (size_t)B_DIM * IN_DIM * 2 + (size_t)HID_DIM * IN_DIM * 2 +
                        (size_t)OUT_DIM * HID_DIM * 2 + (size_t)B_DIM * HID_DIM * 2; // 96 MB
    const size_t perExp = (size_t)2 * B_DIM * OUT_DIM * 2;   // 32 MB (2 bf16 slices)
    // Tier group size by available workspace. ws >= 160 MB verified in-session (R2/R3).
    int G;
    if      (ws_size >= base + 4 * perExp) G = 4;   // 224 MB
    else if (ws_size >= base + 2 * perExp) G = 2;   // 160 MB (verified)
    else if (ws_size >= base + 1 * perExp) G = 1;   // 128 MB
    else                                   G = 0;   // fallback: 128^2 GEMM2, bf16 y

    cvt_bf16<<<(B_DIM * IN_DIM / 4 + 255) / 256, 256, 0, stream>>>(x, xb, B_DIM * IN_DIM / 4);

    if (G > 0) {
        for (int e0 = 0; e0 < NEXP; e0 += G) {
            for (int i = 0; i < G; ++i) {
                const int e = e0 + i;
                transpose_cvt2<<<dim3(HID_DIM / 32, IN_DIM / 32, 2), 256, 0, stream>>>(
                    W1 + (size_t)e * IN_DIM * HID_DIM, w1t,
                    W2 + (size_t)e * HID_DIM * OUT_DIM, w2t);
                // h = xb @ W1[e] + b1[e]   (M=8192, N=4096, K=1024)
                gemm256_8ph<0><<<dim3(HID_DIM / 256, B_DIM / 256, 1), 512, 0, stream>>>(
                    xb, w1t, b1 + (size_t)e * HID_DIM, h,
                    B_DIM, HID_DIM, IN_DIM, IN_DIM, IN_DIM);
                // h = gelu(ln(h))
                ln_gelu_hid<<<B_DIM, 256, 0, stream>>>(h, g1 + (size_t)e * HID_DIM,
                                                       be1 + (size_t)e * HID_DIM);
                // P[i][s] = h @ W2[e] (K-slice s of 2048), bf16 partials
                gemm256_8ph<1><<<dim3(OUT_DIM / 256, B_DIM / 256, 2), 512, 0, stream>>>(
                    h, w2t, nullptr, P + (size_t)i * 2 * B_DIM * OUT_DIM,
                    B_DIM, OUT_DIM, HID_DIM, HID_DIM, HID_DIM / 2);
            }
            // out (+)= sum_i wts[:,e0+i] * gelu(ln(P[i,0]+P[i,1]+b2[e0+i]))
            ln_gelu_combine_g<<<B_DIM, 256, 0, stream>>>(
                P, g2, be2, b2, wts, out, e0, G, e0 == 0 ? 1 : 0);
        }
    } else {
        for (int e = 0; e < NEXP; ++e) {
            transpose_cvt2<<<dim3(HID_DIM / 32, IN_DIM / 32, 2), 256, 0, stream>>>(
                W1 + (size_t)e * IN_DIM * HID_DIM, w1t,
                W2 + (size_t)e * HID_DIM * OUT_DIM, w2t);
            gemm256_8ph<0><<<dim3(HID_DIM / 256, B_DIM / 256, 1), 512, 0, stream>>>(
                xb, w1t, b1 + (size_t)e * HID_DIM, h,
                B_DIM, HID_DIM, IN_DIM, IN_DIM, IN_DIM);
            ln_gelu_hid<<<B_DIM, 256, 0, stream>>>(h, g1 + (size_t)e * HID_DIM,
                                                   be1 + (size_t)e * HID_DIM);
            gemm_bt_bias<<<dim3(OUT_DIM / 128, B_DIM / 128), 256, 0, stream>>>(
                h, w2t, b2 + (size_t)e * OUT_DIM, y, B_DIM, OUT_DIM, HID_DIM);
            ln_gelu_combine<<<B_DIM, 256, 0, stream>>>(y, g2 + (size_t)e * OUT_DIM,
                                                       be2 + (size_t)e * OUT_DIM, wts, out,
                                                       e, e == 0 ? 1 : 0);
        }
    }
}